// Round 26
// baseline (58.212 us; speedup 1.0000x reference)
//
#include <hip/hip_runtime.h>
#include <hip/hip_bf16.h>

#define NROWS 8192
#define DIM 512
#define BM 256
#define BN 256

typedef int   i32x4 __attribute__((ext_vector_type(4)));
typedef int   i32x8 __attribute__((ext_vector_type(8)));
typedef float f32x4 __attribute__((ext_vector_type(4)));
typedef float f32x16 __attribute__((ext_vector_type(16)));

#define FP8_SCALE_1 0x7f7f7f7f   // E8M0 127 = 2^0 in all 4 bytes

// ---------- Phase 1: normalize -> fp8 -> 32-row fragment-linear layout ----------
// Unified layout for A and B (2KB lane-major blocks, 32x32x64 fragments):
//   addr = ((panel*8 + kf)*8 + grp)*2048 + sel*1024 + laneT*16 + byte
// fragment spec: lane l holds row (l&31), k = kf*64 + (l>>5)*32 + sel*16 + byte.
// 256 blocks x 512 thr; block owns 32 rows (one grp). Unit-stride float4 reads,
// padded-LDS stage, coalesced 1KB fragment writes.
__global__ __launch_bounds__(512) void prep_k(
    const float* __restrict__ q, const float* __restrict__ p,
    char* __restrict__ qf, char* __restrict__ pf,
    float* __restrict__ diag) {
  __shared__ char ldsq[32 * 528];
  __shared__ char ldsp[32 * 528];
  const int tid = threadIdx.x;
  const int blk = blockIdx.x;
  const int rr = tid >> 4;              // 0..31: row in group
  const int cs = tid & 15;              // 16 threads per row
  const int i  = blk * 32 + rr;         // global row
  const float4* qr = (const float4*)(q + (size_t)i * DIM);
  const float4* pr = (const float4*)(p + (size_t)i * DIM);

  float4 qv[8], pv[8];
  float ssq = 0.0f, ssp = 0.0f, dt = 0.0f;
  #pragma unroll
  for (int jj = 0; jj < 8; ++jj) {
    qv[jj] = qr[jj * 16 + cs];          // unit-stride across 16 lanes
    pv[jj] = pr[jj * 16 + cs];
    ssq += qv[jj].x*qv[jj].x + qv[jj].y*qv[jj].y + qv[jj].z*qv[jj].z + qv[jj].w*qv[jj].w;
    ssp += pv[jj].x*pv[jj].x + pv[jj].y*pv[jj].y + pv[jj].z*pv[jj].z + pv[jj].w*pv[jj].w;
    dt  += qv[jj].x*pv[jj].x + qv[jj].y*pv[jj].y + qv[jj].z*pv[jj].z + qv[jj].w*pv[jj].w;
  }
  #pragma unroll
  for (int m = 1; m < 16; m <<= 1) {    // 16-lane butterfly (lanes of one row)
    ssq += __shfl_xor(ssq, m, 64);
    ssp += __shfl_xor(ssp, m, 64);
    dt  += __shfl_xor(dt,  m, 64);
  }
  const float invq = 1.0f / fmaxf(sqrtf(ssq), 1e-8f);
  const float invp = 1.0f / fmaxf(sqrtf(ssp), 1e-8f);
  if (cs == 0) diag[i] = dt * invq * invp * 20.0f;

  #pragma unroll
  for (int jj = 0; jj < 8; ++jj) {
    int rq = 0, rp = 0;
    rq = __builtin_amdgcn_cvt_pk_fp8_f32(qv[jj].x * invq, qv[jj].y * invq, rq, false);
    rq = __builtin_amdgcn_cvt_pk_fp8_f32(qv[jj].z * invq, qv[jj].w * invq, rq, true);
    rp = __builtin_amdgcn_cvt_pk_fp8_f32(pv[jj].x * invp, pv[jj].y * invp, rp, false);
    rp = __builtin_amdgcn_cvt_pk_fp8_f32(pv[jj].z * invp, pv[jj].w * invp, rp, true);
    *(unsigned int*)(ldsq + rr * 528 + jj * 64 + cs * 4) = (unsigned int)rq;
    *(unsigned int*)(ldsp + rr * 528 + jj * 64 + cs * 4) = (unsigned int)rp;
  }
  __syncthreads();

  // coalesced fragment writes: 1024 x 16B chunks per operand (8kf x 2sel x 64laneT)
  const int panel = blk >> 3, grp = blk & 7;
  #pragma unroll
  for (int u = 0; u < 2; ++u) {
    const int o = 2 * tid + u;
    const int kf = o >> 7, sel = (o >> 6) & 1, laneT = o & 63;
    const int rrs = laneT & 31;
    const int srcoff = kf * 64 + (laneT >> 5) * 32 + sel * 16;
    const size_t addr =
        (((size_t)(panel * 8 + kf) * 8 + grp) * 2048) + sel * 1024 + laneT * 16;
    *(i32x4*)(qf + addr) = *(const i32x4*)(ldsq + rrs * 528 + srcoff);
    *(i32x4*)(pf + addr) = *(const i32x4*)(ldsp + rrs * 528 + srcoff);
  }
}

// ---------- Phase 2: MX-fp8 GEMM, 32x32x64 MFMA, fragment-linear direct loads ----------
// Single-variable change vs the 45.7us r22/r25 gemm: MFMA shape 16x16x128 ->
// 32x32x64. Same FLOPs, same 24 coalesced 1024B loads/iter, but HALF the MFMA
// instructions (16/iter, each ~17cy deep) — probes whether the ~6900cy/iter
// wall is instruction-issue (helps) or data-return (neutral). Epilogue cheaper:
// with mfma(bf, af), lane holds row m = lane&31 FIXED; n = (reg&3)+8*(reg>>2)
// +4*(lane>>5) -> row-sum = 32 reg-adds + 1 shfl_xor(32) per 32-row group.
// 256 blocks (1/CU), 8 waves (2Mx4N), 128x64 out/wave, zero LDS operands,
// zero K-loop barriers, r13 L2-resident XCD map.
__global__ __launch_bounds__(512, 2) void gemm_lse_k(
    const char* __restrict__ qf, const char* __restrict__ pf,
    float* __restrict__ partial) {
  __shared__ float psum[1024];                  // only LDS: 4KB flush buffer
  const int tid = threadIdx.x;
  const int lane = tid & 63, wid = tid >> 6;
  const int wr = wid >> 2, wc = wid & 3;        // 2M x 4N wave grid
  const int l31 = lane & 31;
  const int b = blockIdx.x;
  const int g = b & 7;                          // XCD (round-robin dispatch)
  const int j = b >> 3;                         // 0..31 within XCD
  const int panelA = (g & 3) * 8 + (j & 7);     // A panel (4 blocks share)
  const int bnset  = (g >> 2) * 16 + (j >> 3) * 4;   // 4 B panels (8 share)
  const int bm = panelA * BM;
  const char* aBase = qf + (size_t)panelA * 131072 + (size_t)lane * 16;
  const char* pBase = pf + (size_t)lane * 16;

  f32x16 acc[2][4] = {};                        // [nb][am], transposed
  i32x8 af[4][2], bf[2][2];                     // [am|nb][ksub]

  #pragma unroll 1
  for (int tt = 0; tt < 16; ++tt) {
    const int kt = tt & 3, t = tt >> 2;

    // A: 16 coalesced 1024B loads (4 am x 2 ksub x lo/hi)
    #pragma unroll
    for (int am = 0; am < 4; ++am)
      #pragma unroll
      for (int ks = 0; ks < 2; ++ks) {
        const char* fa = aBase + (size_t)((kt * 2 + ks) * 8 + wr * 4 + am) * 2048;
        const i32x4 lo = *(const i32x4*)(fa);
        const i32x4 hi = *(const i32x4*)(fa + 1024);
        af[am][ks] = __builtin_shufflevector(lo, hi, 0, 1, 2, 3, 4, 5, 6, 7);
      }
    // B: 8 coalesced 1024B loads (2 nb x 2 ksub x lo/hi)
    #pragma unroll
    for (int nb = 0; nb < 2; ++nb)
      #pragma unroll
      for (int ks = 0; ks < 2; ++ks) {
        const char* fb = pBase +
            (size_t)(((bnset + t) * 8 + kt * 2 + ks) * 8 + wc * 2 + nb) * 2048;
        const i32x4 lo = *(const i32x4*)(fb);
        const i32x4 hi = *(const i32x4*)(fb + 1024);
        bf[nb][ks] = __builtin_shufflevector(lo, hi, 0, 1, 2, 3, 4, 5, 6, 7);
      }

    __builtin_amdgcn_s_setprio(1);
    #pragma unroll
    for (int nb = 0; nb < 2; ++nb)
      #pragma unroll
      for (int am = 0; am < 4; ++am)
        #pragma unroll
        for (int ks = 0; ks < 2; ++ks)
          acc[nb][am] = __builtin_amdgcn_mfma_scale_f32_32x32x64_f8f6f4(
              bf[nb][ks], af[am][ks], acc[nb][am], 0, 0,
              0, FP8_SCALE_1, 0, FP8_SCALE_1);
    __builtin_amdgcn_s_setprio(0);

    if ((tt & 3) == 3) {
      // ---- flush output tile t: exp(20c-20) + row-sum + store ----
      // Lane rows m = wr*128 + am*32 + l31 (fixed); cols n = wc*64 + nb*32
      //   + (reg&3) + 8*(reg>>2) + 4*(lane>>5).
      const int bxc = bnset + t;
      #pragma unroll
      for (int am = 0; am < 4; ++am) {
        float s = 0.0f;
        #pragma unroll
        for (int nb = 0; nb < 2; ++nb)
          #pragma unroll
          for (int r = 0; r < 16; ++r)
            s += __expf(acc[nb][am][r] * 20.0f - 20.0f);
        s += __shfl_xor(s, 32, 64);
        if (lane < 32)
          psum[wc * 256 + wr * 128 + am * 32 + l31] = s;
      }
      __syncthreads();
      if (tid < 256)
        partial[(size_t)(bm + tid) * 32 + bxc] =
            psum[tid] + psum[256 + tid] + psum[512 + tid] + psum[768 + tid];
      __syncthreads();      // psum safe before next tile's writes
      #pragma unroll
      for (int nb = 0; nb < 2; ++nb)
        #pragma unroll
        for (int am = 0; am < 4; ++am)
          acc[nb][am] = f32x16{0.0f, 0.0f, 0.0f, 0.0f, 0.0f, 0.0f, 0.0f, 0.0f,
                               0.0f, 0.0f, 0.0f, 0.0f, 0.0f, 0.0f, 0.0f, 0.0f};
    }
  }
}

// ---------- Phase 3a: per-row loss ----------
__global__ __launch_bounds__(256) void rowloss_k(
    const float* __restrict__ partial, const float* __restrict__ diag,
    float* __restrict__ rowloss) {
  const int i = blockIdx.x * 256 + threadIdx.x;
  const float4* pr = (const float4*)(partial + (size_t)i * 32);
  float s = 0.0f;
  #pragma unroll
  for (int c = 0; c < 8; ++c) {
    const float4 v = pr[c];
    s += v.x + v.y + v.z + v.w;
  }
  rowloss[i] = __logf(s) + 20.0f - diag[i];
}

// ---------- Phase 3b: mean ----------
__global__ __launch_bounds__(1024) void final_k(
    const float* __restrict__ rowloss, float* __restrict__ out) {
  const int t = threadIdx.x;
  float s = 0.0f;
  #pragma unroll
  for (int j = 0; j < 8; ++j) s += rowloss[t + j * 1024];
  #pragma unroll
  for (int m = 1; m < 64; m <<= 1) s += __shfl_xor(s, m, 64);
  __shared__ float red[16];
  if ((t & 63) == 0) red[t >> 6] = s;
  __syncthreads();
  if (t == 0) {
    float acc = 0.0f;
    #pragma unroll
    for (int w = 0; w < 16; ++w) acc += red[w];
    out[0] = acc * (1.0f / (float)NROWS);
  }
}

extern "C" void kernel_launch(void* const* d_in, const int* in_sizes, int n_in,
                              void* d_out, int out_size, void* d_ws, size_t ws_size,
                              hipStream_t stream) {
  const float* q = (const float*)d_in[0];
  const float* p = (const float*)d_in[1];
  char* w = (char*)d_ws;
  char* qf = w;                                               // 4 MB fp8 frags
  char* pf = w + 4194304;                                     // 4 MB fp8 frags
  float* partial    = (float*)(w + 8388608);                  // 1 MB [8192][32]
  float* diag       = (float*)(w + 9437184);                  // 32 KB
  float* rowloss    = (float*)(w + 9437184 + 32768);          // 32 KB
  float* out = (float*)d_out;

  prep_k<<<NROWS / 32, 512, 0, stream>>>(q, p, qf, pf, diag);
  gemm_lse_k<<<256, 512, 0, stream>>>(qf, pf, partial);
  rowloss_k<<<NROWS / 256, 256, 0, stream>>>(partial, diag, rowloss);
  final_k<<<1, 1024, 0, stream>>>(rowloss, out);
}

// Round 27
// 54.343 us; speedup vs baseline: 1.0712x; 1.0712x over previous
//
#include <hip/hip_runtime.h>
#include <hip/hip_bf16.h>

#define NROWS 8192
#define DIM 512
#define BM 256
#define BN 256

typedef int   i32x4 __attribute__((ext_vector_type(4)));
typedef int   i32x8 __attribute__((ext_vector_type(8)));
typedef float f32x4 __attribute__((ext_vector_type(4)));
typedef float f32x16 __attribute__((ext_vector_type(16)));

#define FP8_SCALE_1 0x7f7f7f7f   // E8M0 127 = 2^0 in all 4 bytes

// ---------- Phase 1: normalize -> fp8 -> 32-row fragment-linear layout ----------
// Output bytes IDENTICAL to r26 (verified absmax 0.0):
//   addr = ((panel*8 + kf)*8 + grp)*2048 + sel*1024 + laneT*16 + byte
//   lane l holds row (l&31), k = kf*64 + (l>>5)*32 + sel*16 + byte.
// Producer reorganized to the fastest measured prep shape (r25): 256 thr,
// 16 rows/block (half a 32-row group, h = blk&1), grid 512, 17KB LDS.
// Fragment-chunk map o = u*256+tid -> (kf,sel,ksub,rrs); laneT = ksub*32+
// h*16+rrs -> consecutive tids write contiguous 256B runs (coalesced).
__global__ __launch_bounds__(256) void prep_k(
    const float* __restrict__ q, const float* __restrict__ p,
    char* __restrict__ qf, char* __restrict__ pf,
    float* __restrict__ diag) {
  __shared__ char ldsq[16 * 528];
  __shared__ char ldsp[16 * 528];
  const int tid = threadIdx.x;
  const int blk = blockIdx.x;
  const int rr = tid >> 4;              // row in block (0..15)
  const int cs = tid & 15;              // 16 threads per row
  const int i  = blk * 16 + rr;         // global row
  const float4* qr = (const float4*)(q + (size_t)i * DIM);
  const float4* pr = (const float4*)(p + (size_t)i * DIM);

  float4 qv[8], pv[8];
  float ssq = 0.0f, ssp = 0.0f, dt = 0.0f;
  #pragma unroll
  for (int jj = 0; jj < 8; ++jj) {
    qv[jj] = qr[jj * 16 + cs];          // unit-stride across 16 lanes
    pv[jj] = pr[jj * 16 + cs];
    ssq += qv[jj].x*qv[jj].x + qv[jj].y*qv[jj].y + qv[jj].z*qv[jj].z + qv[jj].w*qv[jj].w;
    ssp += pv[jj].x*pv[jj].x + pv[jj].y*pv[jj].y + pv[jj].z*pv[jj].z + pv[jj].w*pv[jj].w;
    dt  += qv[jj].x*pv[jj].x + qv[jj].y*pv[jj].y + qv[jj].z*pv[jj].z + qv[jj].w*pv[jj].w;
  }
  #pragma unroll
  for (int m = 1; m < 16; m <<= 1) {
    ssq += __shfl_xor(ssq, m, 64);
    ssp += __shfl_xor(ssp, m, 64);
    dt  += __shfl_xor(dt,  m, 64);
  }
  const float invq = 1.0f / fmaxf(sqrtf(ssq), 1e-8f);
  const float invp = 1.0f / fmaxf(sqrtf(ssp), 1e-8f);
  if (cs == 0) diag[i] = dt * invq * invp * 20.0f;

  #pragma unroll
  for (int jj = 0; jj < 8; ++jj) {
    int rq = 0, rp = 0;
    rq = __builtin_amdgcn_cvt_pk_fp8_f32(qv[jj].x * invq, qv[jj].y * invq, rq, false);
    rq = __builtin_amdgcn_cvt_pk_fp8_f32(qv[jj].z * invq, qv[jj].w * invq, rq, true);
    rp = __builtin_amdgcn_cvt_pk_fp8_f32(pv[jj].x * invp, pv[jj].y * invp, rp, false);
    rp = __builtin_amdgcn_cvt_pk_fp8_f32(pv[jj].z * invp, pv[jj].w * invp, rp, true);
    *(unsigned int*)(ldsq + rr * 528 + jj * 64 + cs * 4) = (unsigned int)rq;
    *(unsigned int*)(ldsp + rr * 528 + jj * 64 + cs * 4) = (unsigned int)rp;
  }
  __syncthreads();

  // fragment-chunk writes: 512 x 16B per operand, contiguous 256B runs
  const int panel = blk >> 4;           // 256-row panel
  const int grp   = (blk >> 1) & 7;     // 32-row group within panel
  const int h     = blk & 1;            // 16-row half within group
  #pragma unroll
  for (int u = 0; u < 2; ++u) {
    const int o = u * 256 + tid;        // 0..511
    const int kf   = o >> 6;            // 8 k-fragments (64B each)
    const int sel  = (o >> 5) & 1;      // lo/hi 1KB half
    const int ksub = (o >> 4) & 1;      // laneT>>5 (k sub-block)
    const int rrs  = o & 15;            // row within this block
    const int laneT = ksub * 32 + h * 16 + rrs;
    const int srcoff = kf * 64 + ksub * 32 + sel * 16;
    const size_t addr =
        (((size_t)(panel * 8 + kf) * 8 + grp) * 2048) + sel * 1024 + laneT * 16;
    *(i32x4*)(qf + addr) = *(const i32x4*)(ldsq + rrs * 528 + srcoff);
    *(i32x4*)(pf + addr) = *(const i32x4*)(ldsp + rrs * 528 + srcoff);
  }
}

// ---------- Phase 2: MX-fp8 GEMM, 32x32x64 MFMA, fragment-linear direct loads ----------
// (r26 gemm verbatim — best measured: 43.9us, MfmaUtil 30, absmax 0.0.)
// 256 blocks (1/CU), 8 waves (2Mx4N), 128x64 out/wave, zero LDS operands,
// zero K-loop barriers, r13 L2-resident XCD map, transposed accumulators:
// lane holds row m = lane&31 fixed -> 1-shuffle row-sum.
__global__ __launch_bounds__(512, 2) void gemm_lse_k(
    const char* __restrict__ qf, const char* __restrict__ pf,
    float* __restrict__ partial) {
  __shared__ float psum[1024];                  // only LDS: 4KB flush buffer
  const int tid = threadIdx.x;
  const int lane = tid & 63, wid = tid >> 6;
  const int wr = wid >> 2, wc = wid & 3;        // 2M x 4N wave grid
  const int l31 = lane & 31;
  const int b = blockIdx.x;
  const int g = b & 7;                          // XCD (round-robin dispatch)
  const int j = b >> 3;                         // 0..31 within XCD
  const int panelA = (g & 3) * 8 + (j & 7);     // A panel (4 blocks share)
  const int bnset  = (g >> 2) * 16 + (j >> 3) * 4;   // 4 B panels (8 share)
  const int bm = panelA * BM;
  const char* aBase = qf + (size_t)panelA * 131072 + (size_t)lane * 16;
  const char* pBase = pf + (size_t)lane * 16;

  f32x16 acc[2][4] = {};                        // [nb][am], transposed
  i32x8 af[4][2], bf[2][2];                     // [am|nb][ksub]

  #pragma unroll 1
  for (int tt = 0; tt < 16; ++tt) {
    const int kt = tt & 3, t = tt >> 2;

    // A: 16 coalesced 1024B loads (4 am x 2 ksub x lo/hi)
    #pragma unroll
    for (int am = 0; am < 4; ++am)
      #pragma unroll
      for (int ks = 0; ks < 2; ++ks) {
        const char* fa = aBase + (size_t)((kt * 2 + ks) * 8 + wr * 4 + am) * 2048;
        const i32x4 lo = *(const i32x4*)(fa);
        const i32x4 hi = *(const i32x4*)(fa + 1024);
        af[am][ks] = __builtin_shufflevector(lo, hi, 0, 1, 2, 3, 4, 5, 6, 7);
      }
    // B: 8 coalesced 1024B loads (2 nb x 2 ksub x lo/hi)
    #pragma unroll
    for (int nb = 0; nb < 2; ++nb)
      #pragma unroll
      for (int ks = 0; ks < 2; ++ks) {
        const char* fb = pBase +
            (size_t)(((bnset + t) * 8 + kt * 2 + ks) * 8 + wc * 2 + nb) * 2048;
        const i32x4 lo = *(const i32x4*)(fb);
        const i32x4 hi = *(const i32x4*)(fb + 1024);
        bf[nb][ks] = __builtin_shufflevector(lo, hi, 0, 1, 2, 3, 4, 5, 6, 7);
      }

    __builtin_amdgcn_s_setprio(1);
    #pragma unroll
    for (int nb = 0; nb < 2; ++nb)
      #pragma unroll
      for (int am = 0; am < 4; ++am)
        #pragma unroll
        for (int ks = 0; ks < 2; ++ks)
          acc[nb][am] = __builtin_amdgcn_mfma_scale_f32_32x32x64_f8f6f4(
              bf[nb][ks], af[am][ks], acc[nb][am], 0, 0,
              0, FP8_SCALE_1, 0, FP8_SCALE_1);
    __builtin_amdgcn_s_setprio(0);

    if ((tt & 3) == 3) {
      // ---- flush output tile t: exp(20c-20) + row-sum + store ----
      // Lane rows m = wr*128 + am*32 + l31 (fixed); cols n = wc*64 + nb*32
      //   + (reg&3) + 8*(reg>>2) + 4*(lane>>5).
      const int bxc = bnset + t;
      #pragma unroll
      for (int am = 0; am < 4; ++am) {
        float s = 0.0f;
        #pragma unroll
        for (int nb = 0; nb < 2; ++nb)
          #pragma unroll
          for (int r = 0; r < 16; ++r)
            s += __expf(acc[nb][am][r] * 20.0f - 20.0f);
        s += __shfl_xor(s, 32, 64);
        if (lane < 32)
          psum[wc * 256 + wr * 128 + am * 32 + l31] = s;
      }
      __syncthreads();
      if (tid < 256)
        partial[(size_t)(bm + tid) * 32 + bxc] =
            psum[tid] + psum[256 + tid] + psum[512 + tid] + psum[768 + tid];
      __syncthreads();      // psum safe before next tile's writes
      #pragma unroll
      for (int nb = 0; nb < 2; ++nb)
        #pragma unroll
        for (int am = 0; am < 4; ++am)
          acc[nb][am] = f32x16{0.0f, 0.0f, 0.0f, 0.0f, 0.0f, 0.0f, 0.0f, 0.0f,
                               0.0f, 0.0f, 0.0f, 0.0f, 0.0f, 0.0f, 0.0f, 0.0f};
    }
  }
}

// ---------- Phase 3a: per-row loss ----------
__global__ __launch_bounds__(256) void rowloss_k(
    const float* __restrict__ partial, const float* __restrict__ diag,
    float* __restrict__ rowloss) {
  const int i = blockIdx.x * 256 + threadIdx.x;
  const float4* pr = (const float4*)(partial + (size_t)i * 32);
  float s = 0.0f;
  #pragma unroll
  for (int c = 0; c < 8; ++c) {
    const float4 v = pr[c];
    s += v.x + v.y + v.z + v.w;
  }
  rowloss[i] = __logf(s) + 20.0f - diag[i];
}

// ---------- Phase 3b: mean ----------
__global__ __launch_bounds__(1024) void final_k(
    const float* __restrict__ rowloss, float* __restrict__ out) {
  const int t = threadIdx.x;
  float s = 0.0f;
  #pragma unroll
  for (int j = 0; j < 8; ++j) s += rowloss[t + j * 1024];
  #pragma unroll
  for (int m = 1; m < 64; m <<= 1) s += __shfl_xor(s, m, 64);
  __shared__ float red[16];
  if ((t & 63) == 0) red[t >> 6] = s;
  __syncthreads();
  if (t == 0) {
    float acc = 0.0f;
    #pragma unroll
    for (int w = 0; w < 16; ++w) acc += red[w];
    out[0] = acc * (1.0f / (float)NROWS);
  }
}

extern "C" void kernel_launch(void* const* d_in, const int* in_sizes, int n_in,
                              void* d_out, int out_size, void* d_ws, size_t ws_size,
                              hipStream_t stream) {
  const float* q = (const float*)d_in[0];
  const float* p = (const float*)d_in[1];
  char* w = (char*)d_ws;
  char* qf = w;                                               // 4 MB fp8 frags
  char* pf = w + 4194304;                                     // 4 MB fp8 frags
  float* partial    = (float*)(w + 8388608);                  // 1 MB [8192][32]
  float* diag       = (float*)(w + 9437184);                  // 32 KB
  float* rowloss    = (float*)(w + 9437184 + 32768);          // 32 KB
  float* out = (float*)d_out;

  prep_k<<<NROWS / 16, 256, 0, stream>>>(q, p, qf, pf, diag);
  gemm_lse_k<<<256, 512, 0, stream>>>(qf, pf, partial);
  rowloss_k<<<NROWS / 256, 256, 0, stream>>>(partial, diag, rowloss);
  final_k<<<1, 1024, 0, stream>>>(rowloss, out);
}